// Round 10
// baseline (3945.959 us; speedup 1.0000x reference)
//
#include <hip/hip_runtime.h>

// RuleRNN: 10 GRU steps + 8 attention hops, B=8192 D=512 R=4000.
// All GEMMs: split-fp16 MFMA, 3 products (hi*hi + hi*lo + lo*hi), fp32 acc.
// Round 10: BK=64 single-buffer (128 KiB, 4 planes x 256x64), m97-style
// 2-barrier loop -> 192 MFMA/wave per stall cluster (6x round 6). 8-slot XOR
// swizzle. 2D-chunked XCD mapping kept. Core order = two BK=32 round-6 tiles
// back-to-back -> identical summation order.

typedef _Float16 f16;
typedef _Float16 f16x8 __attribute__((ext_vector_type(8)));
typedef _Float16 f16x4 __attribute__((ext_vector_type(4)));
typedef float    f32x4 __attribute__((ext_vector_type(4)));

constexpr int BATCH = 8192;
constexpr int DDIM  = 512;
constexpr int D3    = 1536;
constexpr int NRELT = 4000;   // true relation count
constexpr int NRELP = 4096;   // padded (zeros)
constexpr int NHOP  = 8;

#define MFMA16(a,b,c) __builtin_amdgcn_mfma_f32_16x16x32_f16((a),(b),(c),0,0,0)
#define BAR()   __builtin_amdgcn_s_barrier()
#define FENCE() asm volatile("" ::: "memory")
#define VM(n) asm volatile("s_waitcnt vmcnt(" #n ")" ::: "memory")

__device__ __forceinline__ void gll16(const void* g, void* l) {
  __builtin_amdgcn_global_load_lds(
      (const __attribute__((address_space(1))) unsigned int*)g,
      (__attribute__((address_space(3))) unsigned int*)l, 16, 0, 0);
}

// ---------------- prep kernels ----------------
__global__ __launch_bounds__(256) void k_split(const float* __restrict__ src,
                                               f16* __restrict__ hi, f16* __restrict__ lo, int n) {
  int i = blockIdx.x * 256 + threadIdx.x;
  if (i >= n) return;
  float v = src[i];
  f16 h = (f16)v;
  hi[i] = h;
  lo[i] = (f16)(v - (float)h);
}

__global__ __launch_bounds__(256) void k_prep_rel(const float* __restrict__ rel,
    f16* __restrict__ rhi, f16* __restrict__ rlo,
    f16* __restrict__ thi, f16* __restrict__ tlo) {
  int i = blockIdx.x * 256 + threadIdx.x;
  if (i >= NRELP * DDIM) return;
  int r = i >> 9, d = i & 511;
  float v = (r < NRELT) ? rel[i] : 0.f;
  f16 h = (f16)v, l = (f16)(v - (float)h);
  rhi[i] = h; rlo[i] = l;
  thi[(size_t)d * NRELP + r] = h;
  tlo[(size_t)d * NRELP + r] = l;
}

__global__ __launch_bounds__(64) void k_gieos(const float* __restrict__ W,
                                              const float* __restrict__ eos,
                                              float* __restrict__ out) {
  int o = blockIdx.x;
  float s = 0.f;
  for (int i = threadIdx.x; i < DDIM; i += 64) s += W[(size_t)o * DDIM + i] * eos[i];
  for (int off = 32; off; off >>= 1) s += __shfl_xor(s, off);
  if (threadIdx.x == 0) out[o] = s;
}

// ---------------- 256x256 8-wave BK=64 single-buffer GEMM core --------------
// LDS planes: 0=Ah, 1=Al, 2=Bh, 3=Bl, each [256][64] f16 (32 KB), 128 KiB tot.
// Per K-tile: stage 4 planes (16 gll16/thread); vmcnt(0); BAR; for kh in 0,1:
// {24 ds_reads; 96 MFMA (hh,lh,hl)}; BAR. Swizzle: slot8 ^= row&7 both sides.
template<int EPI>
__device__ __forceinline__ void gemm_core(
    const f16* __restrict__ Ahi, const f16* __restrict__ Alo, int lda,
    const f16* __restrict__ Bhi, const f16* __restrict__ Blo, int ldb,
    float* __restrict__ Cout, f16* __restrict__ Chi, f16* __restrict__ Clo,
    int ldc, int m0, int n0, int kst, int nt, f16* lds)
{
  const int tid  = threadIdx.x;
  const int lane = tid & 63;
  const int wave = tid >> 6;
  const int wm = wave >> 2;          // 0..1  (A half: 128 rows)
  const int wn = wave & 3;           // 0..3  (B quarter: 64 rows)
  const int rb = lane & 15;
  const int sl = lane >> 4;          // base k slot 0..3
  const int r8 = lane >> 3;          // staging row-in-8 (0..7)
  const int s8 = (lane & 7) ^ r8;    // pre-swizzled source slot (0..7)

  // stage one plane: 4 x gll16/thread; wave w covers rows w*8+i*64 .. +8
  auto stagePlane = [&](int p, int k0) {
    const f16* src = (p == 0) ? Ahi : (p == 1) ? Alo : (p == 2) ? Bhi : Blo;
    const int ld   = (p < 2) ? lda : ldb;
    const int base = (p < 2) ? m0 : n0;
    f16* pl = lds + (p << 14);                    // plane: 256*64 f16 = 32 KB
    #pragma unroll
    for (int i = 0; i < 4; ++i) {
      const int r0 = wave * 8 + i * 64;
      gll16(src + (size_t)(base + r0 + r8) * ld + k0 + s8 * 8, pl + r0 * 64);
    }
  };
  // swizzled fragment read: plane p, local row lr, k-half kh
  auto rd = [&](int p, int lr, int kh) -> f16x8 {
    const int off = lr * 128 + (((sl + kh * 4) ^ (lr & 7)) << 4);
    return *(const f16x8*)((const char*)(lds + (p << 14)) + off);
  };

  f32x4 acc[8][4] = {};
  f16x8 ah[8], al[8], bh[4], bl[4];
  const int A0 = wm * 128, B0 = wn * 64;

  for (int t = 0; t < nt; ++t) {
    const int k0 = kst + t * 64;
    stagePlane(0, k0); stagePlane(2, k0); stagePlane(1, k0); stagePlane(3, k0);
    VM(0);
    BAR(); FENCE();
    #pragma unroll
    for (int kh = 0; kh < 2; ++kh) {
      #pragma unroll
      for (int f = 0; f < 8; ++f) ah[f] = rd(0, A0 + f * 16 + rb, kh);
      #pragma unroll
      for (int f = 0; f < 4; ++f) bh[f] = rd(2, B0 + f * 16 + rb, kh);
      #pragma unroll
      for (int f = 0; f < 8; ++f) al[f] = rd(1, A0 + f * 16 + rb, kh);
      #pragma unroll
      for (int f = 0; f < 4; ++f) bl[f] = rd(3, B0 + f * 16 + rb, kh);
      __builtin_amdgcn_s_setprio(1);
      #pragma unroll
      for (int m = 0; m < 8; ++m)
        #pragma unroll
        for (int n = 0; n < 4; ++n)
          acc[m][n] = MFMA16(ah[m], bh[n], acc[m][n]);
      #pragma unroll
      for (int m = 0; m < 8; ++m)
        #pragma unroll
        for (int n = 0; n < 4; ++n)
          acc[m][n] = MFMA16(al[m], bh[n], acc[m][n]);
      #pragma unroll
      for (int m = 0; m < 8; ++m)
        #pragma unroll
        for (int n = 0; n < 4; ++n)
          acc[m][n] = MFMA16(ah[m], bl[n], acc[m][n]);
      __builtin_amdgcn_s_setprio(0);
    }
    FENCE(); BAR();   // all waves done reading before next tile's stage lands
  }

  // epilogue: C/D layout col = lane&15, row = (lane>>4)*4 + r
  #pragma unroll
  for (int fm = 0; fm < 8; ++fm)
    #pragma unroll
    for (int fn = 0; fn < 4; ++fn)
      #pragma unroll
      for (int r = 0; r < 4; ++r) {
        const int gr = m0 + wm * 128 + fm * 16 + sl * 4 + r;
        const int gc = n0 + wn * 64 + fn * 16 + rb;
        const float v = acc[fm][fn][r];
        if constexpr (EPI == 0) {
          Cout[(size_t)gr * ldc + gc] = v;
        } else {
          const f16 vh = (f16)v;
          Chi[(size_t)gr * ldc + gc] = vh;
          Clo[(size_t)gr * ldc + gc] = (f16)(v - (float)vh);
        }
      }
}

// 2D-chunked XCD mapping: grid 32(m) x gy(n) x gz(z); each XCD processes
// TM x TN super-tiles; m fastest within chunk. Requires (TM*TN) | (nblocks/8).
template<int EPI, int TM, int TN>
__global__ __launch_bounds__(512, 2)
void k_gemm8(const f16* __restrict__ Ahi, const f16* __restrict__ Alo, int lda,
             const f16* __restrict__ Bhi, const f16* __restrict__ Blo, int ldb,
             float* __restrict__ Cout, f16* __restrict__ Chi, f16* __restrict__ Clo,
             int ldc, int K, int gy)
{
  __shared__ __align__(16) f16 lds[4 * 256 * 64];
  const int bid = blockIdx.x;
  const int xcd = bid & 7;
  const int j   = bid >> 3;
  const int within = j % (TM * TN);
  const int st  = xcd + 8 * (j / (TM * TN));   // global super-tile id
  const int nl  = within / TM;
  const int r   = within % TM;
  const int gmx = 32 / TM;
  const int gmn = gy / TN;
  const int z   = st / (gmx * gmn);
  const int rem = st % (gmx * gmn);
  const int bn  = rem / gmx;
  const int bm  = rem % gmx;
  const int m = bm * TM + r;
  const int n = bn * TN + nl;
  float* Co = Cout ? Cout + (size_t)z * BATCH * (size_t)ldc : nullptr;
  gemm_core<EPI>(Ahi, Alo, lda, Bhi, Blo, ldb, Co, Chi, Clo, ldc,
                 m * 256, n * 256, z * K, K / 64, lds);
}

// fused GRU pair: gi = x@Wih^T, gh = h@Whh^T (each N=1536 -> 6 n-blocks).
__global__ __launch_bounds__(512, 2)
void k_gemm8_gru(const f16* __restrict__ xhi, const f16* __restrict__ xlo,
                 const f16* __restrict__ hhi, const f16* __restrict__ hlo,
                 const f16* __restrict__ wihhi, const f16* __restrict__ wihlo,
                 const f16* __restrict__ whhhi, const f16* __restrict__ whhlo,
                 float* __restrict__ gi, float* __restrict__ gh)
{
  __shared__ __align__(16) f16 lds[4 * 256 * 64];
  const int bid = blockIdx.x;                       // 384 blocks, C=48=TM*TN
  const int xcd = bid & 7;
  const int j   = bid >> 3;                         // 0..47
  const int nl  = j / 8;                            // 0..5
  const int r   = j % 8;
  const int bn  = xcd / 4;                          // 0..1
  const int bm  = xcd % 4;                          // 0..3
  const int m   = bm * 8 + r;                       // 0..31
  const int nn  = bn * 6 + nl;                      // 0..11
  const bool second = nn >= 6;
  gemm_core<0>(second ? hhi : xhi, second ? hlo : xlo, DDIM,
               second ? whhhi : wihhi, second ? whhlo : wihlo, DDIM,
               second ? gh : gi, nullptr, nullptr, D3,
               m * 256, (second ? nn - 6 : nn) * 256, 0, DDIM / 64, lds);
}

// ---------------- softmax: S planes (f16 hi/lo) -> P planes in place --------
__global__ __launch_bounds__(256)
void k_softmax(f16* __restrict__ Shi, f16* __restrict__ Slo) {
  const int row = blockIdx.x;
  f16* phi = Shi + (size_t)row * NRELP;
  f16* plo = Slo + (size_t)row * NRELP;
  const int tid = threadIdx.x, lane = tid & 63, wv = tid >> 6;
  const int ng = (tid < 232) ? 4 : 3;     // 1000 groups of 4 cols
  f32x4 v[4];
  float mx = -3.402823e38f;
  #pragma unroll
  for (int i = 0; i < 4; ++i)
    if (i < ng) {
      f16x4 hv = *(const f16x4*)(phi + (tid + 256 * i) * 4);
      f16x4 lv = *(const f16x4*)(plo + (tid + 256 * i) * 4);
      #pragma unroll
      for (int j = 0; j < 4; ++j) v[i][j] = (float)hv[j] + (float)lv[j];
      mx = fmaxf(fmaxf(fmaxf(mx, v[i][0]), fmaxf(v[i][1], v[i][2])), v[i][3]);
    }
  float l = 0.f;
  #pragma unroll
  for (int i = 0; i < 4; ++i)
    if (i < ng)
      l += __expf(v[i][0] - mx) + __expf(v[i][1] - mx)
         + __expf(v[i][2] - mx) + __expf(v[i][3] - mx);
  #pragma unroll
  for (int off = 1; off < 64; off <<= 1) {
    float om = __shfl_xor(mx, off), ol = __shfl_xor(l, off);
    float nm = fmaxf(mx, om);
    l = l * __expf(mx - nm) + ol * __expf(om - nm);
    mx = nm;
  }
  __shared__ float sm[4], slr[4];
  if (lane == 0) { sm[wv] = mx; slr[wv] = l; }
  __syncthreads();
  const float fm = fmaxf(fmaxf(sm[0], sm[1]), fmaxf(sm[2], sm[3]));
  const float fl = slr[0] * __expf(sm[0] - fm) + slr[1] * __expf(sm[1] - fm)
                 + slr[2] * __expf(sm[2] - fm) + slr[3] * __expf(sm[3] - fm);
  const float il = 1.f / fl;
  #pragma unroll
  for (int i = 0; i < 4; ++i)
    if (i < ng) {
      f16x4 oh, ol;
      #pragma unroll
      for (int j = 0; j < 4; ++j) {
        const float pv = __expf(v[i][j] - fm) * il;
        const f16 ph = (f16)pv;
        oh[j] = ph;
        ol[j] = (f16)(pv - (float)ph);
      }
      *(f16x4*)(phi + (tid + 256 * i) * 4) = oh;
      *(f16x4*)(plo + (tid + 256 * i) * 4) = ol;
    }
  if (tid < 24) {   // zero pad cols 4000..4095 in both planes
    f16x4 z = {(f16)0.f, (f16)0.f, (f16)0.f, (f16)0.f};
    *(f16x4*)(phi + (1000 + tid) * 4) = z;
    *(f16x4*)(plo + (1000 + tid) * 4) = z;
  }
}

// ---------------- split-K reduce + subgoal epilogue -------------------------
__global__ __launch_bounds__(256)
void k_subred(const float* __restrict__ Cp, float* __restrict__ outp,
              f16* __restrict__ xhi, f16* __restrict__ xlo, int hop) {
  const int idx = blockIdx.x * 256 + threadIdx.x;    // BATCH*DDIM/4
  const int b = idx >> 7, d4 = (idx & 127) * 4;
  const size_t o = (size_t)b * DDIM + d4;
  f32x4 s = *(const f32x4*)(Cp + o);
  s += *(const f32x4*)(Cp + (size_t)BATCH * DDIM + o);
  s += *(const f32x4*)(Cp + 2 * (size_t)BATCH * DDIM + o);
  s += *(const f32x4*)(Cp + 3 * (size_t)BATCH * DDIM + o);
  *(f32x4*)(outp + (size_t)b * (NHOP * DDIM) + (size_t)hop * DDIM + d4) = s;
  f16x4 vh, vl;
  #pragma unroll
  for (int j = 0; j < 4; ++j) {
    const f16 ph = (f16)s[j];
    vh[j] = ph;
    vl[j] = (f16)(s[j] - (float)ph);
  }
  *(f16x4*)(xhi + o) = vh;
  *(f16x4*)(xlo + o) = vl;
}

// ---------------- GRU gate fusion -------------------------------------------
__global__ __launch_bounds__(256)
void k_gates(const float* __restrict__ gi, const float* __restrict__ givec,
             const float* __restrict__ gh,
             const float* __restrict__ bih, const float* __restrict__ bhh,
             const float* __restrict__ hin, float* __restrict__ hout,
             f16* __restrict__ hhi, f16* __restrict__ hlo)
{
  const int idx = blockIdx.x * 256 + threadIdx.x;   // over BATCH*DDIM/4
  const int b  = idx >> 7;
  const int d4 = (idx & 127) * 4;
  f32x4 ir, iz, inn;
  if (gi) {
    const float* g = gi + (size_t)b * D3 + d4;
    ir  = *(const f32x4*)(g);
    iz  = *(const f32x4*)(g + DDIM);
    inn = *(const f32x4*)(g + 2 * DDIM);
  } else {
    ir  = *(const f32x4*)(givec + d4);
    iz  = *(const f32x4*)(givec + DDIM + d4);
    inn = *(const f32x4*)(givec + 2 * DDIM + d4);
  }
  ir  += *(const f32x4*)(bih + d4);
  iz  += *(const f32x4*)(bih + DDIM + d4);
  inn += *(const f32x4*)(bih + 2 * DDIM + d4);
  f32x4 hr = {0.f, 0.f, 0.f, 0.f}, hz = {0.f, 0.f, 0.f, 0.f}, hn = {0.f, 0.f, 0.f, 0.f};
  if (gh) {
    const float* g = gh + (size_t)b * D3 + d4;
    hr = *(const f32x4*)(g);
    hz = *(const f32x4*)(g + DDIM);
    hn = *(const f32x4*)(g + 2 * DDIM);
  }
  hr += *(const f32x4*)(bhh + d4);
  hz += *(const f32x4*)(bhh + DDIM + d4);
  hn += *(const f32x4*)(bhh + 2 * DDIM + d4);
  f32x4 hp = {0.f, 0.f, 0.f, 0.f};
  if (hin) hp = *(const f32x4*)(hin + (size_t)b * DDIM + d4);
  f32x4 hv; f16x4 vh, vl;
  #pragma unroll
  for (int j = 0; j < 4; ++j) {
    const float r = 1.f / (1.f + __expf(-(ir[j] + hr[j])));
    const float z = 1.f / (1.f + __expf(-(iz[j] + hz[j])));
    const float n = tanhf(inn[j] + r * hn[j]);
    const float h = (1.f - z) * n + z * hp[j];
    hv[j] = h;
    const f16 ph = (f16)h;
    vh[j] = ph;
    vl[j] = (f16)(h - (float)ph);
  }
  *(f32x4*)(hout + (size_t)b * DDIM + d4) = hv;
  *(f16x4*)(hhi + (size_t)b * DDIM + d4) = vh;
  *(f16x4*)(hlo + (size_t)b * DDIM + d4) = vl;
}

__global__ __launch_bounds__(256) void k_ones(float* __restrict__ o, int n) {
  int i = blockIdx.x * 256 + threadIdx.x;
  if (i < n) o[i] = 1.0f;
}

// ---------------- host ------------------------------------------------------
extern "C" void kernel_launch(void* const* d_in, const int* in_sizes, int n_in,
                              void* d_out, int out_size, void* d_ws, size_t ws_size,
                              hipStream_t stream)
{
  const float* query = (const float*)d_in[0];
  const float* W_ih  = (const float*)d_in[1];
  const float* W_hh  = (const float*)d_in[2];
  const float* b_ih  = (const float*)d_in[3];
  const float* b_hh  = (const float*)d_in[4];
  const float* rel   = (const float*)d_in[5];
  const float* eos   = (const float*)d_in[6];
  float* out = (float*)d_out;
  (void)in_sizes; (void)n_in; (void)out_size; (void)ws_size;

  // workspace layout (~262 MB)
  char* w = (char*)d_ws;
  f16* SPhi    = (f16*)w;   w += (size_t)BATCH * NRELP * 2;   // 64MB S/P hi; gi/gh alias
  f16* SPlo    = (f16*)w;   w += (size_t)BATCH * NRELP * 2;   // 64MB S/P lo
  float* Cpart = (float*)w; w += (size_t)4 * BATCH * DDIM * 4;// 64MB split-K partials
  float* hbuf  = (float*)w; w += (size_t)BATCH * DDIM * 4;
  f16* h_hi    = (f16*)w;   w += (size_t)BATCH * DDIM * 2;
  f16* h_lo    = (f16*)w;   w += (size_t)BATCH * DDIM * 2;
  f16* x_hi    = (f16*)w;   w += (size_t)BATCH * DDIM * 2;    // query, then subgoal
  f16* x_lo    = (f16*)w;   w += (size_t)BATCH * DDIM * 2;
  f16* wih_hi  = (f16*)w;   w += (size_t)D3 * DDIM * 2;
  f16* wih_lo  = (f16*)w;   w += (size_t)D3 * DDIM * 2;
  f16* whh_hi  = (f16*)w;   w += (size_t)D3 * DDIM * 2;
  f16* whh_lo  = (f16*)w;   w += (size_t)D3 * DDIM * 2;
  f16* rel_hi  = (f16*)w;   w += (size_t)NRELP * DDIM * 2;
  f16* rel_lo  = (f16*)w;   w += (size_t)NRELP * DDIM * 2;
  f16* relT_hi = (f16*)w;   w += (size_t)DDIM * NRELP * 2;
  f16* relT_lo = (f16*)w;   w += (size_t)DDIM * NRELP * 2;
  float* gieos = (float*)w; w += (size_t)D3 * 4;
  float* gi = (float*)SPhi;               // S/P planes dead when gi/gh live
  float* gh = (float*)SPhi + (size_t)BATCH * D3;

  // prep
  k_split<<<(BATCH * DDIM + 255) / 256, 256, 0, stream>>>(query, x_hi, x_lo, BATCH * DDIM);
  k_split<<<(D3 * DDIM + 255) / 256, 256, 0, stream>>>(W_ih, wih_hi, wih_lo, D3 * DDIM);
  k_split<<<(D3 * DDIM + 255) / 256, 256, 0, stream>>>(W_hh, whh_hi, whh_lo, D3 * DDIM);
  k_prep_rel<<<(NRELP * DDIM + 255) / 256, 256, 0, stream>>>(rel, rel_hi, rel_lo, relT_hi, relT_lo);
  k_gieos<<<D3, 64, 0, stream>>>(W_ih, eos, gieos);

  const int ggrid = BATCH * DDIM / 4 / 256;

  // step A: h1 = GRU(query, 0)   (192 blocks, gy=6: TM=4, TN=6)
  k_gemm8<0, 4, 6><<<192, 512, 0, stream>>>(x_hi, x_lo, DDIM, wih_hi, wih_lo, DDIM,
      gi, nullptr, nullptr, D3, DDIM, 6);
  k_gates<<<ggrid, 256, 0, stream>>>(gi, nullptr, nullptr, b_ih, b_hh, nullptr, hbuf, h_hi, h_lo);

  // step B: h = GRU(eos, h1)
  k_gemm8<0, 4, 6><<<192, 512, 0, stream>>>(h_hi, h_lo, DDIM, whh_hi, whh_lo, DDIM,
      gh, nullptr, nullptr, D3, DDIM, 6);
  k_gates<<<ggrid, 256, 0, stream>>>(nullptr, gieos, gh, b_ih, b_hh, hbuf, hbuf, h_hi, h_lo);

  for (int hop = 0; hop < NHOP; ++hop) {
    // score = h @ relation^T -> S as f16 hi/lo (512 blocks, gy=16: TM=8, TN=8)
    k_gemm8<1, 8, 8><<<512, 512, 0, stream>>>(h_hi, h_lo, DDIM, rel_hi, rel_lo, DDIM,
        nullptr, SPhi, SPlo, NRELP, DDIM, 16);
    // P = softmax(S), hi/lo in place
    k_softmax<<<BATCH, 256, 0, stream>>>(SPhi, SPlo);
    // subgoal partials: P @ relT^T, split-K=4 (256 blocks, gy=2: TM=8, TN=2)
    k_gemm8<0, 8, 2><<<256, 512, 0, stream>>>(SPhi, SPlo, NRELP,
        relT_hi, relT_lo, NRELP, Cpart, nullptr, nullptr, DDIM, 1024, 2);
    // reduce partials -> d_out[:,hop,:] + x hi/lo splits
    k_subred<<<ggrid, 256, 0, stream>>>(Cpart, out, x_hi, x_lo, hop);
    // fused GRU pair: gi = subgoal @ W_ih^T ; gh = h @ W_hh^T
    k_gemm8_gru<<<384, 512, 0, stream>>>(x_hi, x_lo, h_hi, h_lo,
        wih_hi, wih_lo, whh_hi, whh_lo, gi, gh);
    k_gates<<<ggrid, 256, 0, stream>>>(gi, nullptr, gh, b_ih, b_hh, hbuf, hbuf, h_hi, h_lo);
  }

  // masks = 1.0
  k_ones<<<(BATCH * NHOP + 255) / 256, 256, 0, stream>>>(out + (size_t)BATCH * NHOP * DDIM, BATCH * NHOP);
}

// Round 12
// 3193.114 us; speedup vs baseline: 1.2358x; 1.2358x over previous
//
#include <hip/hip_runtime.h>

// RuleRNN: 10 GRU steps + 8 attention hops, B=8192 D=512 R=4000.
// Round 12: round-11's m201-geometry concatenated-K GEMM with CORRECT gating:
// stage units = {B all rows, A-even bands, A-odd bands} matching per-phase
// read footprints; counted gates VM(2)/VM(4) with 2-3 phase leads; 4 phases x
// 16 MFMA; reads+stage between barrier pairs; dbuf 128 KiB; chunked XCD map.

typedef _Float16 f16;
typedef _Float16 f16x8 __attribute__((ext_vector_type(8)));
typedef _Float16 f16x4 __attribute__((ext_vector_type(4)));
typedef float    f32x4 __attribute__((ext_vector_type(4)));

constexpr int BATCH = 8192;
constexpr int DDIM  = 512;
constexpr int D3    = 1536;
constexpr int NRELT = 4000;   // true relation count
constexpr int NRELP = 4096;   // padded (zeros)
constexpr int NHOP  = 8;

#define MFMA16(a,b,c) __builtin_amdgcn_mfma_f32_16x16x32_f16((a),(b),(c),0,0,0)
#define BAR()   __builtin_amdgcn_s_barrier()
#define FENCE() asm volatile("" ::: "memory")
#define SCHED0() __builtin_amdgcn_sched_barrier(0)
#define VM(n) asm volatile("s_waitcnt vmcnt(" #n ")" ::: "memory")
#define LGKM0() asm volatile("s_waitcnt lgkmcnt(0)" ::: "memory")

__device__ __forceinline__ void gll16(const void* g, void* l) {
  __builtin_amdgcn_global_load_lds(
      (const __attribute__((address_space(1))) unsigned int*)g,
      (__attribute__((address_space(3))) unsigned int*)l, 16, 0, 0);
}

// ---------------- prep kernels ----------------
__global__ __launch_bounds__(256) void k_split(const float* __restrict__ src,
                                               f16* __restrict__ hi, f16* __restrict__ lo, int n) {
  int i = blockIdx.x * 256 + threadIdx.x;
  if (i >= n) return;
  float v = src[i];
  f16 h = (f16)v;
  hi[i] = h;
  lo[i] = (f16)(v - (float)h);
}

__global__ __launch_bounds__(256) void k_prep_rel(const float* __restrict__ rel,
    f16* __restrict__ rhi, f16* __restrict__ rlo,
    f16* __restrict__ thi, f16* __restrict__ tlo) {
  int i = blockIdx.x * 256 + threadIdx.x;
  if (i >= NRELP * DDIM) return;
  int r = i >> 9, d = i & 511;
  float v = (r < NRELT) ? rel[i] : 0.f;
  f16 h = (f16)v, l = (f16)(v - (float)h);
  rhi[i] = h; rlo[i] = l;
  thi[(size_t)d * NRELP + r] = h;
  tlo[(size_t)d * NRELP + r] = l;
}

__global__ __launch_bounds__(64) void k_gieos(const float* __restrict__ W,
                                              const float* __restrict__ eos,
                                              float* __restrict__ out) {
  int o = blockIdx.x;
  float s = 0.f;
  for (int i = threadIdx.x; i < DDIM; i += 64) s += W[(size_t)o * DDIM + i] * eos[i];
  for (int off = 32; off; off >>= 1) s += __shfl_xor(s, off);
  if (threadIdx.x == 0) out[o] = s;
}

// ---------------- 256x256 m201-style GEMM core over concatenated K ----------
// Virtual K' = 3*Kphys: seg0 = Ah*Bh, seg1 = Ah*Bl, seg2 = Al*Bh.
// tpsl = log2(Kphys/64). LDS/buffer: A[256][64] + B[256][64] f16 = 64 KB;
// 2 buffers = 128 KiB. Swizzle: stored slot = src slot ^ (row&7).
// Stage units (rows): B = all 256 (4 gll16/thr); A-even = [0,64)u[128,192);
// A-odd = [64,128)u[192,256) (2 gll16/thr each). Per-phase read footprints:
// ph0/ph2 read A-even + B (ks0/ks1), ph1/ph3 read A-odd.
// Issue (for t+1): B@ph0, Aeven@ph1, Aodd@ph2. Gates: tile-boundary VM(2)
// (B,Aeven of next tile done; Aodd in flight), ph0 VM(4) (Aodd of cur done).
template<int EPI>
__device__ __forceinline__ void gemm_core(
    const f16* __restrict__ Ahi, const f16* __restrict__ Alo, int lda,
    const f16* __restrict__ Bhi, const f16* __restrict__ Blo, int ldb,
    float* __restrict__ Cout, f16* __restrict__ Chi, f16* __restrict__ Clo,
    int ldc, int m0, int n0, int gt0, int nt, int tpsl, f16* lds)
{
  const int tid  = threadIdx.x;
  const int lane = tid & 63;
  const int wave = tid >> 6;
  const int wm = wave >> 2;          // 0..1  (A half: 128 rows)
  const int wn = wave & 3;           // 0..3  (B quarter: 64 rows)
  const int rb = lane & 15;
  const int sl4 = lane >> 4;         // k slot 0..3 within 32-k step
  const int srow = lane >> 3;        // row within 8-row staging block (0..7)
  const int s8 = (lane & 7) ^ srow;  // pre-swizzled source slot

  // A source for virtual tile gt
  auto asrc = [&](int gt) -> const f16* { return (gt >> tpsl) == 2 ? Alo : Ahi; };
  auto bsrc = [&](int gt) -> const f16* { return (gt >> tpsl) == 1 ? Blo : Bhi; };
  auto kof  = [&](int gt) -> int { return (gt & ((1 << tpsl) - 1)) << 6; };

  // stage B: all 256 rows (4 loads/thread)
  auto stageB = [&](int buf, int gt) {
    const f16* src = bsrc(gt);
    const int kk = kof(gt);
    f16* pl = lds + buf * 32768 + 16384;
    #pragma unroll
    for (int i = 0; i < 4; ++i) {
      const int r0 = wave * 8 + i * 64;
      gll16(src + (size_t)(n0 + r0 + srow) * ldb + kk + s8 * 8, pl + r0 * 64);
    }
  };
  // stage A even bands: rows [0,64) u [128,192)   (2 loads/thread)
  // stage A odd  bands: rows [64,128) u [192,256)
  auto stageA = [&](int buf, int gt, int odd) {
    const f16* src = asrc(gt);
    const int kk = kof(gt);
    f16* pl = lds + buf * 32768;
    #pragma unroll
    for (int i = 0; i < 2; ++i) {
      const int r0 = odd * 64 + i * 128 + wave * 8;
      gll16(src + (size_t)(m0 + r0 + srow) * lda + kk + s8 * 8, pl + r0 * 64);
    }
  };
  // swizzled fragment read: local row lr (0..255), k-step ks (0..1)
  auto rd = [&](int buf, int isA, int lr, int ks) -> f16x8 {
    const f16* pl = lds + buf * 32768 + (isA ? 0 : 16384);
    const int off = lr * 128 + (((ks * 4 + sl4) ^ (lr & 7)) << 4);
    return *(const f16x8*)((const char*)pl + off);
  };

  // prologue: tile gt0 -> buf 0, issue B, Aeven, Aodd; gate B+Aeven
  stageB(0, gt0); stageA(0, gt0, 0); stageA(0, gt0, 1);
  VM(2);
  BAR(); FENCE();

  f32x4 acc[8][4] = {};
  f16x8 a[4], b[4];
  const int A0r = wm * 128, B0r = wn * 64;

  for (int t = 0; t < nt; ++t) {
    const int cb = t & 1;
    const bool more = (t + 1 < nt);
    const int gt1 = gt0 + t + 1;

    // ---- ph0: pre-reads a(m0-3,ks0)[Aeven] + b(ks0)[B]; issue B(t+1);
    //           gate Aodd(t); MFMA m0-3 ks0
    #pragma unroll
    for (int f = 0; f < 4; ++f) a[f] = rd(cb, 1, A0r + f * 16 + rb, 0);
    #pragma unroll
    for (int f = 0; f < 4; ++f) b[f] = rd(cb, 0, B0r + f * 16 + rb, 0);
    if (more) { stageB(cb ^ 1, gt1); VM(4); } else { VM(0); }
    FENCE(); BAR(); LGKM0(); SCHED0();
    __builtin_amdgcn_s_setprio(1);
    #pragma unroll
    for (int m = 0; m < 4; ++m)
      #pragma unroll
      for (int n = 0; n < 4; ++n)
        acc[m][n] = MFMA16(a[m], b[n], acc[m][n]);
    __builtin_amdgcn_s_setprio(0);
    FENCE(); BAR(); FENCE();

    // ---- ph1: pre-reads a(m4-7,ks0)[Aodd]; issue Aeven(t+1); MFMA m4-7 ks0
    #pragma unroll
    for (int f = 0; f < 4; ++f) a[f] = rd(cb, 1, A0r + 64 + f * 16 + rb, 0);
    if (more) stageA(cb ^ 1, gt1, 0);
    FENCE(); BAR(); LGKM0(); SCHED0();
    __builtin_amdgcn_s_setprio(1);
    #pragma unroll
    for (int m = 0; m < 4; ++m)
      #pragma unroll
      for (int n = 0; n < 4; ++n)
        acc[4 + m][n] = MFMA16(a[m], b[n], acc[4 + m][n]);
    __builtin_amdgcn_s_setprio(0);
    FENCE(); BAR(); FENCE();

    // ---- ph2: pre-reads a(m0-3,ks1)[Aeven] + b(ks1)[B]; issue Aodd(t+1);
    //           MFMA m0-3 ks1
    #pragma unroll
    for (int f = 0; f < 4; ++f) a[f] = rd(cb, 1, A0r + f * 16 + rb, 1);
    #pragma unroll
    for (int f = 0; f < 4; ++f) b[f] = rd(cb, 0, B0r + f * 16 + rb, 1);
    if (more) stageA(cb ^ 1, gt1, 1);
    FENCE(); BAR(); LGKM0(); SCHED0();
    __builtin_amdgcn_s_setprio(1);
    #pragma unroll
    for (int m = 0; m < 4; ++m)
      #pragma unroll
      for (int n = 0; n < 4; ++n)
        acc[m][n] = MFMA16(a[m], b[n], acc[m][n]);
    __builtin_amdgcn_s_setprio(0);
    FENCE(); BAR(); FENCE();

    // ---- ph3: pre-reads a(m4-7,ks1)[Aodd]; MFMA m4-7 ks1; tile-boundary gate
    #pragma unroll
    for (int f = 0; f < 4; ++f) a[f] = rd(cb, 1, A0r + 64 + f * 16 + rb, 1);
    FENCE(); BAR(); LGKM0(); SCHED0();
    __builtin_amdgcn_s_setprio(1);
    #pragma unroll
    for (int m = 0; m < 4; ++m)
      #pragma unroll
      for (int n = 0; n < 4; ++n)
        acc[4 + m][n] = MFMA16(a[m], b[n], acc[4 + m][n]);
    __builtin_amdgcn_s_setprio(0);
    if (more) { VM(2); }   // B(t+1), Aeven(t+1) done; Aodd(t+1) in flight
    FENCE(); BAR(); FENCE();
  }

  // epilogue: C/D layout col = lane&15, row = (lane>>4)*4 + r
  #pragma unroll
  for (int fm = 0; fm < 8; ++fm)
    #pragma unroll
    for (int fn = 0; fn < 4; ++fn)
      #pragma unroll
      for (int r = 0; r < 4; ++r) {
        const int gr = m0 + wm * 128 + fm * 16 + sl4 * 4 + r;
        const int gc = n0 + wn * 64 + fn * 16 + rb;
        const float v = acc[fm][fn][r];
        if constexpr (EPI == 0) {
          Cout[(size_t)gr * ldc + gc] = v;
        } else {
          const f16 vh = (f16)v;
          Chi[(size_t)gr * ldc + gc] = vh;
          Clo[(size_t)gr * ldc + gc] = (f16)(v - (float)vh);
        }
      }
}

// 2D-chunked XCD mapping: grid 32(m) x gy(n) x gz(z); each XCD processes
// TM x TN super-tiles; m fastest within chunk. Requires (TM*TN) | (nblocks/8).
template<int EPI, int TM, int TN>
__global__ __launch_bounds__(512, 1)
void k_gemm8(const f16* __restrict__ Ahi, const f16* __restrict__ Alo, int lda,
             const f16* __restrict__ Bhi, const f16* __restrict__ Blo, int ldb,
             float* __restrict__ Cout, f16* __restrict__ Chi, f16* __restrict__ Clo,
             int ldc, int nt, int tpsl, int gy)
{
  __shared__ __align__(16) f16 lds[2 * 32768];
  const int bid = blockIdx.x;
  const int xcd = bid & 7;
  const int j   = bid >> 3;
  const int within = j % (TM * TN);
  const int st  = xcd + 8 * (j / (TM * TN));   // global super-tile id
  const int nl  = within / TM;
  const int r   = within % TM;
  const int gmx = 32 / TM;
  const int gmn = gy / TN;
  const int z   = st / (gmx * gmn);
  const int rem = st % (gmx * gmn);
  const int bn  = rem / gmx;
  const int bm  = rem % gmx;
  const int m = bm * TM + r;
  const int n = bn * TN + nl;
  float* Co = Cout ? Cout + (size_t)z * BATCH * (size_t)ldc : nullptr;
  gemm_core<EPI>(Ahi, Alo, lda, Bhi, Blo, ldb, Co, Chi, Clo, ldc,
                 m * 256, n * 256, z * nt, nt, tpsl, lds);
}

// fused GRU pair: gi = x@Wih^T, gh = h@Whh^T (each N=1536 -> 6 n-blocks).
__global__ __launch_bounds__(512, 1)
void k_gemm8_gru(const f16* __restrict__ xhi, const f16* __restrict__ xlo,
                 const f16* __restrict__ hhi, const f16* __restrict__ hlo,
                 const f16* __restrict__ wihhi, const f16* __restrict__ wihlo,
                 const f16* __restrict__ whhhi, const f16* __restrict__ whhlo,
                 float* __restrict__ gi, float* __restrict__ gh)
{
  __shared__ __align__(16) f16 lds[2 * 32768];
  const int bid = blockIdx.x;                       // 384 blocks, C=48=TM*TN
  const int xcd = bid & 7;
  const int j   = bid >> 3;                         // 0..47
  const int nl  = j / 8;                            // 0..5
  const int r   = j % 8;
  const int bn  = xcd / 4;                          // 0..1
  const int bm  = xcd % 4;                          // 0..3
  const int m   = bm * 8 + r;                       // 0..31
  const int nn  = bn * 6 + nl;                      // 0..11
  const bool second = nn >= 6;
  gemm_core<0>(second ? hhi : xhi, second ? hlo : xlo, DDIM,
               second ? whhhi : wihhi, second ? whhlo : wihlo, DDIM,
               second ? gh : gi, nullptr, nullptr, D3,
               m * 256, (second ? nn - 6 : nn) * 256, 0, 24, 3, lds);
}

// ---------------- softmax: S planes (f16 hi/lo) -> P planes in place --------
__global__ __launch_bounds__(256)
void k_softmax(f16* __restrict__ Shi, f16* __restrict__ Slo) {
  const int row = blockIdx.x;
  f16* phi = Shi + (size_t)row * NRELP;
  f16* plo = Slo + (size_t)row * NRELP;
  const int tid = threadIdx.x, lane = tid & 63, wv = tid >> 6;
  const int ng = (tid < 232) ? 4 : 3;     // 1000 groups of 4 cols
  f32x4 v[4];
  float mx = -3.402823e38f;
  #pragma unroll
  for (int i = 0; i < 4; ++i)
    if (i < ng) {
      f16x4 hv = *(const f16x4*)(phi + (tid + 256 * i) * 4);
      f16x4 lv = *(const f16x4*)(plo + (tid + 256 * i) * 4);
      #pragma unroll
      for (int j = 0; j < 4; ++j) v[i][j] = (float)hv[j] + (float)lv[j];
      mx = fmaxf(fmaxf(fmaxf(mx, v[i][0]), fmaxf(v[i][1], v[i][2])), v[i][3]);
    }
  float l = 0.f;
  #pragma unroll
  for (int i = 0; i < 4; ++i)
    if (i < ng)
      l += __expf(v[i][0] - mx) + __expf(v[i][1] - mx)
         + __expf(v[i][2] - mx) + __expf(v[i][3] - mx);
  #pragma unroll
  for (int off = 1; off < 64; off <<= 1) {
    float om = __shfl_xor(mx, off), ol = __shfl_xor(l, off);
    float nm = fmaxf(mx, om);
    l = l * __expf(mx - nm) + ol * __expf(om - nm);
    mx = nm;
  }
  __shared__ float sm[4], slr[4];
  if (lane == 0) { sm[wv] = mx; slr[wv] = l; }
  __syncthreads();
  const float fm = fmaxf(fmaxf(sm[0], sm[1]), fmaxf(sm[2], sm[3]));
  const float fl = slr[0] * __expf(sm[0] - fm) + slr[1] * __expf(sm[1] - fm)
                 + slr[2] * __expf(sm[2] - fm) + slr[3] * __expf(sm[3] - fm);
  const float il = 1.f / fl;
  #pragma unroll
  for (int i = 0; i < 4; ++i)
    if (i < ng) {
      f16x4 oh, ol;
      #pragma unroll
      for (int j = 0; j < 4; ++j) {
        const float pv = __expf(v[i][j] - fm) * il;
        const f16 ph = (f16)pv;
        oh[j] = ph;
        ol[j] = (f16)(pv - (float)ph);
      }
      *(f16x4*)(phi + (tid + 256 * i) * 4) = oh;
      *(f16x4*)(plo + (tid + 256 * i) * 4) = ol;
    }
  if (tid < 24) {   // zero pad cols 4000..4095 in both planes
    f16x4 z = {(f16)0.f, (f16)0.f, (f16)0.f, (f16)0.f};
    *(f16x4*)(phi + (1000 + tid) * 4) = z;
    *(f16x4*)(plo + (1000 + tid) * 4) = z;
  }
}

// ---------------- split-K reduce + subgoal epilogue -------------------------
__global__ __launch_bounds__(256)
void k_subred(const float* __restrict__ Cp, float* __restrict__ outp,
              f16* __restrict__ xhi, f16* __restrict__ xlo, int hop) {
  const int idx = blockIdx.x * 256 + threadIdx.x;    // BATCH*DDIM/4
  const int b = idx >> 7, d4 = (idx & 127) * 4;
  const size_t o = (size_t)b * DDIM + d4;
  f32x4 s = *(const f32x4*)(Cp + o);
  s += *(const f32x4*)(Cp + (size_t)BATCH * DDIM + o);
  s += *(const f32x4*)(Cp + 2 * (size_t)BATCH * DDIM + o);
  s += *(const f32x4*)(Cp + 3 * (size_t)BATCH * DDIM + o);
  *(f32x4*)(outp + (size_t)b * (NHOP * DDIM) + (size_t)hop * DDIM + d4) = s;
  f16x4 vh, vl;
  #pragma unroll
  for (int j = 0; j < 4; ++j) {
    const f16 ph = (f16)s[j];
    vh[j] = ph;
    vl[j] = (f16)(s[j] - (float)ph);
  }
  *(f16x4*)(xhi + o) = vh;
  *(f16x4*)(xlo + o) = vl;
}

// ---------------- GRU gate fusion -------------------------------------------
__global__ __launch_bounds__(256)
void k_gates(const float* __restrict__ gi, const float* __restrict__ givec,
             const float* __restrict__ gh,
             const float* __restrict__ bih, const float* __restrict__ bhh,
             const float* __restrict__ hin, float* __restrict__ hout,
             f16* __restrict__ hhi, f16* __restrict__ hlo)
{
  const int idx = blockIdx.x * 256 + threadIdx.x;   // over BATCH*DDIM/4
  const int b  = idx >> 7;
  const int d4 = (idx & 127) * 4;
  f32x4 ir, iz, inn;
  if (gi) {
    const float* g = gi + (size_t)b * D3 + d4;
    ir  = *(const f32x4*)(g);
    iz  = *(const f32x4*)(g + DDIM);
    inn = *(const f32x4*)(g + 2 * DDIM);
  } else {
    ir  = *(const f32x4*)(givec + d4);
    iz  = *(const f32x4*)(givec + DDIM + d4);
    inn = *(const f32x4*)(givec + 2 * DDIM + d4);
  }
  ir  += *(const f32x4*)(bih + d4);
  iz  += *(const f32x4*)(bih + DDIM + d4);
  inn += *(const f32x4*)(bih + 2 * DDIM + d4);
  f32x4 hr = {0.f, 0.f, 0.f, 0.f}, hz = {0.f, 0.f, 0.f, 0.f}, hn = {0.f, 0.f, 0.f, 0.f};
  if (gh) {
    const float* g = gh + (size_t)b * D3 + d4;
    hr = *(const f32x4*)(g);
    hz = *(const f32x4*)(g + DDIM);
    hn = *(const f32x4*)(g + 2 * DDIM);
  }
  hr += *(const f32x4*)(bhh + d4);
  hz += *(const f32x4*)(bhh + DDIM + d4);
  hn += *(const f32x4*)(bhh + 2 * DDIM + d4);
  f32x4 hp = {0.f, 0.f, 0.f, 0.f};
  if (hin) hp = *(const f32x4*)(hin + (size_t)b * DDIM + d4);
  f32x4 hv; f16x4 vh, vl;
  #pragma unroll
  for (int j = 0; j < 4; ++j) {
    const float r = 1.f / (1.f + __expf(-(ir[j] + hr[j])));
    const float z = 1.f / (1.f + __expf(-(iz[j] + hz[j])));
    const float n = tanhf(inn[j] + r * hn[j]);
    const float h = (1.f - z) * n + z * hp[j];
    hv[j] = h;
    const f16 ph = (f16)h;
    vh[j] = ph;
    vl[j] = (f16)(h - (float)ph);
  }
  *(f32x4*)(hout + (size_t)b * DDIM + d4) = hv;
  *(f16x4*)(hhi + (size_t)b * DDIM + d4) = vh;
  *(f16x4*)(hlo + (size_t)b * DDIM + d4) = vl;
}

__global__ __launch_bounds__(256) void k_ones(float* __restrict__ o, int n) {
  int i = blockIdx.x * 256 + threadIdx.x;
  if (i < n) o[i] = 1.0f;
}

// ---------------- host ------------------------------------------------------
extern "C" void kernel_launch(void* const* d_in, const int* in_sizes, int n_in,
                              void* d_out, int out_size, void* d_ws, size_t ws_size,
                              hipStream_t stream)
{
  const float* query = (const float*)d_in[0];
  const float* W_ih  = (const float*)d_in[1];
  const float* W_hh  = (const float*)d_in[2];
  const float* b_ih  = (const float*)d_in[3];
  const float* b_hh  = (const float*)d_in[4];
  const float* rel   = (const float*)d_in[5];
  const float* eos   = (const float*)d_in[6];
  float* out = (float*)d_out;
  (void)in_sizes; (void)n_in; (void)out_size; (void)ws_size;

  // workspace layout (~262 MB)
  char* w = (char*)d_ws;
  f16* SPhi    = (f16*)w;   w += (size_t)BATCH * NRELP * 2;   // 64MB S/P hi; gi/gh alias
  f16* SPlo    = (f16*)w;   w += (size_t)BATCH * NRELP * 2;   // 64MB S/P lo
  float* Cpart = (float*)w; w += (size_t)4 * BATCH * DDIM * 4;// 64MB split-K partials
  float* hbuf  = (float*)w; w += (size_t)BATCH * DDIM * 4;
  f16* h_hi    = (f16*)w;   w += (size_t)BATCH * DDIM * 2;
  f16* h_lo    = (f16*)w;   w += (size_t)BATCH * DDIM * 2;
  f16* x_hi    = (f16*)w;   w += (size_t)BATCH * DDIM * 2;    // query, then subgoal
  f16* x_lo    = (f16*)w;   w += (size_t)BATCH * DDIM * 2;
  f16* wih_hi  = (f16*)w;   w += (size_t)D3 * DDIM * 2;
  f16* wih_lo  = (f16*)w;   w += (size_t)D3 * DDIM * 2;
  f16* whh_hi  = (f16*)w;   w += (size_t)D3 * DDIM * 2;
  f16* whh_lo  = (f16*)w;   w += (size_t)D3 * DDIM * 2;
  f16* rel_hi  = (f16*)w;   w += (size_t)NRELP * DDIM * 2;
  f16* rel_lo  = (f16*)w;   w += (size_t)NRELP * DDIM * 2;
  f16* relT_hi = (f16*)w;   w += (size_t)DDIM * NRELP * 2;
  f16* relT_lo = (f16*)w;   w += (size_t)DDIM * NRELP * 2;
  float* gieos = (float*)w; w += (size_t)D3 * 4;
  float* gi = (float*)SPhi;               // S/P planes dead when gi/gh live
  float* gh = (float*)SPhi + (size_t)BATCH * D3;

  // prep
  k_split<<<(BATCH * DDIM + 255) / 256, 256, 0, stream>>>(query, x_hi, x_lo, BATCH * DDIM);
  k_split<<<(D3 * DDIM + 255) / 256, 256, 0, stream>>>(W_ih, wih_hi, wih_lo, D3 * DDIM);
  k_split<<<(D3 * DDIM + 255) / 256, 256, 0, stream>>>(W_hh, whh_hi, whh_lo, D3 * DDIM);
  k_prep_rel<<<(NRELP * DDIM + 255) / 256, 256, 0, stream>>>(rel, rel_hi, rel_lo, relT_hi, relT_lo);
  k_gieos<<<D3, 64, 0, stream>>>(W_ih, eos, gieos);

  const int ggrid = BATCH * DDIM / 4 / 256;

  // step A: h1 = GRU(query, 0)   (192 blocks, gy=6: TM=4, TN=6; K'=1536)
  k_gemm8<0, 4, 6><<<192, 512, 0, stream>>>(x_hi, x_lo, DDIM, wih_hi, wih_lo, DDIM,
      gi, nullptr, nullptr, D3, 24, 3, 6);
  k_gates<<<ggrid, 256, 0, stream>>>(gi, nullptr, nullptr, b_ih, b_hh, nullptr, hbuf, h_hi, h_lo);

  // step B: h = GRU(eos, h1)
  k_gemm8<0, 4, 6><<<192, 512, 0, stream>>>(h_hi, h_lo, DDIM, whh_hi, whh_lo, DDIM,
      gh, nullptr, nullptr, D3, 24, 3, 6);
  k_gates<<<ggrid, 256, 0, stream>>>(nullptr, gieos, gh, b_ih, b_hh, hbuf, hbuf, h_hi, h_lo);

  for (int hop = 0; hop < NHOP; ++hop) {
    // score = h @ relation^T -> S as f16 hi/lo (512 blocks; K'=1536)
    k_gemm8<1, 8, 8><<<512, 512, 0, stream>>>(h_hi, h_lo, DDIM, rel_hi, rel_lo, DDIM,
        nullptr, SPhi, SPlo, NRELP, 24, 3, 16);
    // P = softmax(S), hi/lo in place
    k_softmax<<<BATCH, 256, 0, stream>>>(SPhi, SPlo);
    // subgoal partials: P @ relT^T, split-K=4 (256 blocks; K'=12288, 48 t/z)
    k_gemm8<0, 8, 2><<<256, 512, 0, stream>>>(SPhi, SPlo, NRELP,
        relT_hi, relT_lo, NRELP, Cpart, nullptr, nullptr, DDIM, 48, 6, 2);
    // reduce partials -> d_out[:,hop,:] + x hi/lo splits
    k_subred<<<ggrid, 256, 0, stream>>>(Cpart, out, x_hi, x_lo, hop);
    // fused GRU pair: gi = subgoal @ W_ih^T ; gh = h @ W_hh^T
    k_gemm8_gru<<<384, 512, 0, stream>>>(x_hi, x_lo, h_hi, h_lo,
        wih_hi, wih_lo, whh_hi, whh_lo, gi, gh);
    k_gates<<<ggrid, 256, 0, stream>>>(gi, nullptr, gh, b_ih, b_hh, hbuf, hbuf, h_hi, h_lo);
  }

  // masks = 1.0
  k_ones<<<(BATCH * NHOP + 255) / 256, 256, 0, stream>>>(out + (size_t)BATCH * NHOP * DDIM, BATCH * NHOP);
}

// Round 13
// 2955.461 us; speedup vs baseline: 1.3351x; 1.0804x over previous
//
#include <hip/hip_runtime.h>

// RuleRNN: 10 GRU steps + 8 attention hops, B=8192 D=512 R=4000.
// All GEMMs: split-fp16 MFMA, 3 products (hi*hi + hi*lo + lo*hi), fp32 acc.
// Round 13: GEMM = round-9 exactly (3-phase counted vmcnt, 2D-chunked XCD
// map; best measured 2970us). Aux rework: LDS-tiled relation transpose
// (was 8KB-stride 2B scatter) + f16x8-vectorized softmax.

typedef _Float16 f16;
typedef _Float16 f16x8 __attribute__((ext_vector_type(8)));
typedef _Float16 f16x4 __attribute__((ext_vector_type(4)));
typedef float    f32x4 __attribute__((ext_vector_type(4)));

constexpr int BATCH = 8192;
constexpr int DDIM  = 512;
constexpr int D3    = 1536;
constexpr int NRELT = 4000;   // true relation count
constexpr int NRELP = 4096;   // padded (zeros)
constexpr int NHOP  = 8;

#define MFMA16(a,b,c) __builtin_amdgcn_mfma_f32_16x16x32_f16((a),(b),(c),0,0,0)
#define BAR()   __builtin_amdgcn_s_barrier()
#define FENCE() asm volatile("" ::: "memory")
#define SCHED0() __builtin_amdgcn_sched_barrier(0)
#define VM(n) asm volatile("s_waitcnt vmcnt(" #n ")" ::: "memory")

__device__ __forceinline__ void gll16(const void* g, void* l) {
  __builtin_amdgcn_global_load_lds(
      (const __attribute__((address_space(1))) unsigned int*)g,
      (__attribute__((address_space(3))) unsigned int*)l, 16, 0, 0);
}

// ---------------- prep kernels ----------------
__global__ __launch_bounds__(256) void k_split(const float* __restrict__ src,
                                               f16* __restrict__ hi, f16* __restrict__ lo, int n) {
  int i = blockIdx.x * 256 + threadIdx.x;
  if (i >= n) return;
  float v = src[i];
  f16 h = (f16)v;
  hi[i] = h;
  lo[i] = (f16)(v - (float)h);
}

// relation -> padded [4096][512] hi/lo planes (coalesced; pad rows zero)
__global__ __launch_bounds__(256) void k_prep_rel(const float* __restrict__ rel,
    f16* __restrict__ rhi, f16* __restrict__ rlo) {
  int i = blockIdx.x * 256 + threadIdx.x;
  if (i >= NRELP * DDIM) return;
  int r = i >> 9;
  float v = (r < NRELT) ? rel[i] : 0.f;
  f16 h = (f16)v;
  rhi[i] = h; rlo[i] = (f16)(v - (float)h);
}

// relation -> transposed [512][4096] hi/lo via LDS 64x64 tiles (coalesced)
__global__ __launch_bounds__(256) void k_transpose_rel(const float* __restrict__ rel,
    f16* __restrict__ thi, f16* __restrict__ tlo) {
  __shared__ float t[64][65];
  const int r0 = blockIdx.x * 64;   // relation-row tile
  const int d0 = blockIdx.y * 64;   // dim tile
  const int tid = threadIdx.x;
  const int lr = tid >> 4, c4 = (tid & 15) * 4;
  #pragma unroll
  for (int p = 0; p < 4; ++p) {
    const int r = r0 + lr + p * 16;
    f32x4 v = {0.f, 0.f, 0.f, 0.f};
    if (r < NRELT) v = *(const f32x4*)(rel + (size_t)r * DDIM + d0 + c4);
    *(f32x4*)&t[lr + p * 16][c4] = v;
  }
  __syncthreads();
  const int ld  = tid >> 2;          // local d (output row) 0..63
  const int rr0 = (tid & 3) * 16;    // 16 consecutive r per thread
  f16x8 oh0, oh1, ol0, ol1;
  #pragma unroll
  for (int j = 0; j < 8; ++j) {
    float v0 = t[rr0 + j][ld];
    float v1 = t[rr0 + 8 + j][ld];
    f16 h0 = (f16)v0, h1 = (f16)v1;
    oh0[j] = h0; ol0[j] = (f16)(v0 - (float)h0);
    oh1[j] = h1; ol1[j] = (f16)(v1 - (float)h1);
  }
  const size_t o = (size_t)(d0 + ld) * NRELP + r0 + rr0;
  *(f16x8*)(thi + o) = oh0;
  *(f16x8*)(thi + o + 8) = oh1;
  *(f16x8*)(tlo + o) = ol0;
  *(f16x8*)(tlo + o + 8) = ol1;
}

__global__ __launch_bounds__(64) void k_gieos(const float* __restrict__ W,
                                              const float* __restrict__ eos,
                                              float* __restrict__ out) {
  int o = blockIdx.x;
  float s = 0.f;
  for (int i = threadIdx.x; i < DDIM; i += 64) s += W[(size_t)o * DDIM + i] * eos[i];
  for (int off = 32; off; off >>= 1) s += __shfl_xor(s, off);
  if (threadIdx.x == 0) out[o] = s;
}

// ---------------- 256x256 8-wave 3-phase counted-vmcnt GEMM core ------------
// (round-9/round-6 core, best measured)
template<int EPI>
__device__ __forceinline__ void gemm_core(
    const f16* __restrict__ Ahi, const f16* __restrict__ Alo, int lda,
    const f16* __restrict__ Bhi, const f16* __restrict__ Blo, int ldb,
    float* __restrict__ Cout, f16* __restrict__ Chi, f16* __restrict__ Clo,
    int ldc, int m0, int n0, int kst, int nt, f16* lds)
{
  const int tid  = threadIdx.x;
  const int lane = tid & 63;
  const int wave = tid >> 6;
  const int wm = wave >> 2;          // 0..1  (A half: 128 rows)
  const int wn = wave & 3;           // 0..3  (B quarter: 64 rows)
  const int rb = lane & 15;
  const int sl = lane >> 4;          // k slot 0..3 (8 f16 each)
  const int srow = lane >> 2;        // staging row within 16-row chunk

  auto stage2 = [&](int buf, int p, int k0) {
    const f16* src = (p == 0) ? Ahi : (p == 1) ? Alo : (p == 2) ? Bhi : Blo;
    const int ld   = (p < 2) ? lda : ldb;
    const int base = (p < 2) ? m0 : n0;
    f16* pl = lds + ((buf * 4 + p) << 13);       // plane: 256*32 f16
    #pragma unroll
    for (int c = 0; c < 2; ++c) {
      const int r0 = wave * 16 + c * 128;
      const int lr = r0 + srow;
      const int slot = (lane & 3) ^ ((lr >> 1) & 3);
      gll16(src + (size_t)(base + lr) * ld + k0 + slot * 8, pl + r0 * 32);
    }
  };
  auto rd = [&](int buf, int p, int lr) -> f16x8 {
    const int off = lr * 64 + ((sl ^ ((lr >> 1) & 3)) << 4);
    return *(const f16x8*)((const char*)(lds + ((buf * 4 + p) << 13)) + off);
  };

  // prologue: tile 0, issue order Ah, Bh, Al, Bl
  stage2(0, 0, kst); stage2(0, 2, kst); stage2(0, 1, kst); stage2(0, 3, kst);

  f32x4 acc[8][4] = {};
  f16x8 ah[8], al[8], bh[4], bl[4];
  const int A0 = wm * 128, B0 = wn * 64;

  for (int t = 0; t < nt; ++t) {
    const int cur = t & 1;
    const int nxt = cur ^ 1;
    const bool more = (t + 1 < nt);
    const int kn = kst + (t + 1) * 32;

    // ---- ph0: stage Ah,Bh(t+1); gate {Ah,Bh}(t); read ah[8],bh[4]; 32 MFMA hh
    if (more) { stage2(nxt, 0, kn); stage2(nxt, 2, kn); VM(8); } else { VM(4); }
    BAR(); FENCE();
    #pragma unroll
    for (int f = 0; f < 8; ++f) ah[f] = rd(cur, 0, A0 + f * 16 + rb);
    #pragma unroll
    for (int f = 0; f < 4; ++f) bh[f] = rd(cur, 2, B0 + f * 16 + rb);
    __builtin_amdgcn_s_setprio(1);
    #pragma unroll
    for (int m = 0; m < 8; ++m)
      #pragma unroll
      for (int n = 0; n < 4; ++n)
        acc[m][n] = MFMA16(ah[m], bh[n], acc[m][n]);
    __builtin_amdgcn_s_setprio(0);
    SCHED0();

    // ---- ph1: stage Al(t+1); gate {Al}(t); read al[8]; 32 MFMA lh
    if (more) { stage2(nxt, 1, kn); VM(8); } else { VM(2); }
    BAR(); FENCE();
    #pragma unroll
    for (int f = 0; f < 8; ++f) al[f] = rd(cur, 1, A0 + f * 16 + rb);
    __builtin_amdgcn_s_setprio(1);
    #pragma unroll
    for (int m = 0; m < 8; ++m)
      #pragma unroll
      for (int n = 0; n < 4; ++n)
        acc[m][n] = MFMA16(al[m], bh[n], acc[m][n]);
    __builtin_amdgcn_s_setprio(0);
    SCHED0();

    // ---- ph2: stage Bl(t+1); gate {Bl}(t); read bl[4]; 32 MFMA hl
    if (more) { stage2(nxt, 3, kn); VM(8); } else { VM(0); }
    BAR(); FENCE();
    #pragma unroll
    for (int f = 0; f < 4; ++f) bl[f] = rd(cur, 3, B0 + f * 16 + rb);
    __builtin_amdgcn_s_setprio(1);
    #pragma unroll
    for (int m = 0; m < 8; ++m)
      #pragma unroll
      for (int n = 0; n < 4; ++n)
        acc[m][n] = MFMA16(ah[m], bl[n], acc[m][n]);
    __builtin_amdgcn_s_setprio(0);
    SCHED0();
  }

  // epilogue: C/D layout col = lane&15, row = (lane>>4)*4 + r
  #pragma unroll
  for (int fm = 0; fm < 8; ++fm)
    #pragma unroll
    for (int fn = 0; fn < 4; ++fn)
      #pragma unroll
      for (int r = 0; r < 4; ++r) {
        const int gr = m0 + wm * 128 + fm * 16 + sl * 4 + r;
        const int gc = n0 + wn * 64 + fn * 16 + rb;
        const float v = acc[fm][fn][r];
        if constexpr (EPI == 0) {
          Cout[(size_t)gr * ldc + gc] = v;
        } else {
          const f16 vh = (f16)v;
          Chi[(size_t)gr * ldc + gc] = vh;
          Clo[(size_t)gr * ldc + gc] = (f16)(v - (float)vh);
        }
      }
}

// 2D-chunked XCD mapping: grid 32(m) x gy(n) x gz(z); each XCD processes
// TM x TN super-tiles; m fastest within chunk. Requires (TM*TN) | (nblocks/8).
template<int EPI, int TM, int TN>
__global__ __launch_bounds__(512, 2)
void k_gemm8(const f16* __restrict__ Ahi, const f16* __restrict__ Alo, int lda,
             const f16* __restrict__ Bhi, const f16* __restrict__ Blo, int ldb,
             float* __restrict__ Cout, f16* __restrict__ Chi, f16* __restrict__ Clo,
             int ldc, int K, int gy)
{
  __shared__ __align__(16) f16 lds[2 * 4 * 256 * 32];
  const int bid = blockIdx.x;
  const int xcd = bid & 7;
  const int j   = bid >> 3;
  const int within = j % (TM * TN);
  const int st  = xcd + 8 * (j / (TM * TN));   // global super-tile id
  const int nl  = within / TM;
  const int r   = within % TM;
  const int gmx = 32 / TM;
  const int gmn = gy / TN;
  const int z   = st / (gmx * gmn);
  const int rem = st % (gmx * gmn);
  const int bn  = rem / gmx;
  const int bm  = rem % gmx;
  const int m = bm * TM + r;
  const int n = bn * TN + nl;
  float* Co = Cout ? Cout + (size_t)z * BATCH * (size_t)ldc : nullptr;
  gemm_core<EPI>(Ahi, Alo, lda, Bhi, Blo, ldb, Co, Chi, Clo, ldc,
                 m * 256, n * 256, z * K, K / 32, lds);
}

// fused GRU pair: gi = x@Wih^T, gh = h@Whh^T (each N=1536 -> 6 n-blocks).
__global__ __launch_bounds__(512, 2)
void k_gemm8_gru(const f16* __restrict__ xhi, const f16* __restrict__ xlo,
                 const f16* __restrict__ hhi, const f16* __restrict__ hlo,
                 const f16* __restrict__ wihhi, const f16* __restrict__ wihlo,
                 const f16* __restrict__ whhhi, const f16* __restrict__ whhlo,
                 float* __restrict__ gi, float* __restrict__ gh)
{
  __shared__ __align__(16) f16 lds[2 * 4 * 256 * 32];
  const int bid = blockIdx.x;                       // 384 blocks, C=48=TM*TN
  const int xcd = bid & 7;
  const int j   = bid >> 3;                         // 0..47
  const int nl  = j / 8;                            // 0..5
  const int r   = j % 8;
  const int bn  = xcd / 4;                          // 0..1
  const int bm  = xcd % 4;                          // 0..3
  const int m   = bm * 8 + r;                       // 0..31
  const int nn  = bn * 6 + nl;                      // 0..11
  const bool second = nn >= 6;
  gemm_core<0>(second ? hhi : xhi, second ? hlo : xlo, DDIM,
               second ? whhhi : wihhi, second ? whhlo : wihlo, DDIM,
               second ? gh : gi, nullptr, nullptr, D3,
               m * 256, (second ? nn - 6 : nn) * 256, 0, DDIM / 32, lds);
}

// ---------------- softmax: S planes (f16 hi/lo) -> P planes in place --------
// f16x8 accesses; uniform 2-chunk sweep (cols tid*8 and 2048+tid*8);
// pad cols (>=4000) masked to -inf -> exp underflows to exact 0.
__global__ __launch_bounds__(256)
void k_softmax(f16* __restrict__ Shi, f16* __restrict__ Slo) {
  const int row = blockIdx.x;
  f16* phi = Shi + (size_t)row * NRELP;
  f16* plo = Slo + (size_t)row * NRELP;
  const int tid = threadIdx.x, lane = tid & 63, wv = tid >> 6;
  const int b0 = tid * 8, b1 = 2048 + tid * 8;
  f16x8 h0 = *(const f16x8*)(phi + b0);
  f16x8 l0 = *(const f16x8*)(plo + b0);
  f16x8 h1 = *(const f16x8*)(phi + b1);
  f16x8 l1 = *(const f16x8*)(plo + b1);
  float v[16];
  float mx = -3.402823e38f;
  #pragma unroll
  for (int j = 0; j < 8; ++j) {
    v[j] = (float)h0[j] + (float)l0[j];
    mx = fmaxf(mx, v[j]);
  }
  #pragma unroll
  for (int j = 0; j < 8; ++j) {
    const float x = (b1 + j < NRELT) ? (float)h1[j] + (float)l1[j] : -3.402823e38f;
    v[8 + j] = x;
    mx = fmaxf(mx, x);
  }
  float l = 0.f;
  #pragma unroll
  for (int j = 0; j < 16; ++j) l += __expf(v[j] - mx);
  #pragma unroll
  for (int off = 1; off < 64; off <<= 1) {
    float om = __shfl_xor(mx, off), ol = __shfl_xor(l, off);
    float nm = fmaxf(mx, om);
    l = l * __expf(mx - nm) + ol * __expf(om - nm);
    mx = nm;
  }
  __shared__ float sm[4], slr[4];
  if (lane == 0) { sm[wv] = mx; slr[wv] = l; }
  __syncthreads();
  const float fm = fmaxf(fmaxf(sm[0], sm[1]), fmaxf(sm[2], sm[3]));
  const float fl = slr[0] * __expf(sm[0] - fm) + slr[1] * __expf(sm[1] - fm)
                 + slr[2] * __expf(sm[2] - fm) + slr[3] * __expf(sm[3] - fm);
  const float il = 1.f / fl;
  f16x8 oh0, ol0, oh1, ol1;
  #pragma unroll
  for (int j = 0; j < 8; ++j) {
    const float p0 = __expf(v[j] - fm) * il;
    const float p1 = __expf(v[8 + j] - fm) * il;
    const f16 q0 = (f16)p0, q1 = (f16)p1;
    oh0[j] = q0; ol0[j] = (f16)(p0 - (float)q0);
    oh1[j] = q1; ol1[j] = (f16)(p1 - (float)q1);
  }
  *(f16x8*)(phi + b0) = oh0;
  *(f16x8*)(plo + b0) = ol0;
  *(f16x8*)(phi + b1) = oh1;
  *(f16x8*)(plo + b1) = ol1;
}

// ---------------- split-K reduce + subgoal epilogue -------------------------
__global__ __launch_bounds__(256)
void k_subred(const float* __restrict__ Cp, float* __restrict__ outp,
              f16* __restrict__ xhi, f16* __restrict__ xlo, int hop) {
  const int idx = blockIdx.x * 256 + threadIdx.x;    // BATCH*DDIM/4
  const int b = idx >> 7, d4 = (idx & 127) * 4;
  const size_t o = (size_t)b * DDIM + d4;
  f32x4 s = *(const f32x4*)(Cp + o);
  s += *(const f32x4*)(Cp + (size_t)BATCH * DDIM + o);
  s += *(const f32x4*)(Cp + 2 * (size_t)BATCH * DDIM + o);
  s += *(const f32x4*)(Cp + 3 * (size_t)BATCH * DDIM + o);
  *(f32x4*)(outp + (size_t)b * (NHOP * DDIM) + (size_t)hop * DDIM + d4) = s;
  f16x4 vh, vl;
  #pragma unroll
  for (int j = 0; j < 4; ++j) {
    const f16 ph = (f16)s[j];
    vh[j] = ph;
    vl[j] = (f16)(s[j] - (float)ph);
  }
  *(f16x4*)(xhi + o) = vh;
  *(f16x4*)(xlo + o) = vl;
}

// ---------------- GRU gate fusion -------------------------------------------
__global__ __launch_bounds__(256)
void k_gates(const float* __restrict__ gi, const float* __restrict__ givec,
             const float* __restrict__ gh,
             const float* __restrict__ bih, const float* __restrict__ bhh,
             const float* __restrict__ hin, float* __restrict__ hout,
             f16* __restrict__ hhi, f16* __restrict__ hlo)
{
  const int idx = blockIdx.x * 256 + threadIdx.x;   // over BATCH*DDIM/4
  const int b  = idx >> 7;
  const int d4 = (idx & 127) * 4;
  f32x4 ir, iz, inn;
  if (gi) {
    const float* g = gi + (size_t)b * D3 + d4;
    ir  = *(const f32x4*)(g);
    iz  = *(const f32x4*)(g + DDIM);
    inn = *(const f32x4*)(g + 2 * DDIM);
  } else {
    ir  = *(const f32x4*)(givec + d4);
    iz  = *(const f32x4*)(givec + DDIM + d4);
    inn = *(const f32x4*)(givec + 2 * DDIM + d4);
  }
  ir  += *(const f32x4*)(bih + d4);
  iz  += *(const f32x4*)(bih + DDIM + d4);
  inn += *(const f32x4*)(bih + 2 * DDIM + d4);
  f32x4 hr = {0.f, 0.f, 0.f, 0.f}, hz = {0.f, 0.f, 0.f, 0.f}, hn = {0.f, 0.f, 0.f, 0.f};
  if (gh) {
    const float* g = gh + (size_t)b * D3 + d4;
    hr = *(const f32x4*)(g);
    hz = *(const f32x4*)(g + DDIM);
    hn = *(const f32x4*)(g + 2 * DDIM);
  }
  hr += *(const f32x4*)(bhh + d4);
  hz += *(const f32x4*)(bhh + DDIM + d4);
  hn += *(const f32x4*)(bhh + 2 * DDIM + d4);
  f32x4 hp = {0.f, 0.f, 0.f, 0.f};
  if (hin) hp = *(const f32x4*)(hin + (size_t)b * DDIM + d4);
  f32x4 hv; f16x4 vh, vl;
  #pragma unroll
  for (int j = 0; j < 4; ++j) {
    const float r = 1.f / (1.f + __expf(-(ir[j] + hr[j])));
    const float z = 1.f / (1.f + __expf(-(iz[j] + hz[j])));
    const float n = tanhf(inn[j] + r * hn[j]);
    const float h = (1.f - z) * n + z * hp[j];
    hv[j] = h;
    const f16 ph = (f16)h;
    vh[j] = ph;
    vl[j] = (f16)(h - (float)ph);
  }
  *(f32x4*)(hout + (size_t)b * DDIM + d4) = hv;
  *(f16x4*)(hhi + (size_t)b * DDIM + d4) = vh;
  *(f16x4*)(hlo + (size_t)b * DDIM + d4) = vl;
}

__global__ __launch_bounds__(256) void k_ones(float* __restrict__ o, int n) {
  int i = blockIdx.x * 256 + threadIdx.x;
  if (i < n) o[i] = 1.0f;
}

// ---------------- host ------------------------------------------------------
extern "C" void kernel_launch(void* const* d_in, const int* in_sizes, int n_in,
                              void* d_out, int out_size, void* d_ws, size_t ws_size,
                              hipStream_t stream)
{
  const float* query = (const float*)d_in[0];
  const float* W_ih  = (const float*)d_in[1];
  const float* W_hh  = (const float*)d_in[2];
  const float* b_ih  = (const float*)d_in[3];
  const float* b_hh  = (const float*)d_in[4];
  const float* rel   = (const float*)d_in[5];
  const float* eos   = (const float*)d_in[6];
  float* out = (float*)d_out;
  (void)in_sizes; (void)n_in; (void)out_size; (void)ws_size;

  // workspace layout (~262 MB)
  char* w = (char*)d_ws;
  f16* SPhi    = (f16*)w;   w += (size_t)BATCH * NRELP * 2;   // 64MB S/P hi; gi/gh alias
  f16* SPlo    = (f16*)w;   w += (size_t)BATCH * NRELP * 2;   // 64MB S/P lo
  float* Cpart = (float*)w; w += (size_t)4 * BATCH * DDIM * 4;// 64MB split-K partials
  float* hbuf  = (float*)w; w += (size_t)BATCH * DDIM * 4;
  f16* h_hi    = (f16*)w;   w += (size_t)BATCH * DDIM * 2;
  f16* h_lo    = (f16*)w;   w += (size_t)BATCH * DDIM * 2;
  f16* x_hi    = (f16*)w;   w += (size_t)BATCH * DDIM * 2;    // query, then subgoal
  f16* x_lo    = (f16*)w;   w += (size_t)BATCH * DDIM * 2;
  f16* wih_hi  = (f16*)w;   w += (size_t)D3 * DDIM * 2;
  f16* wih_lo  = (f16*)w;   w += (size_t)D3 * DDIM * 2;
  f16* whh_hi  = (f16*)w;   w += (size_t)D3 * DDIM * 2;
  f16* whh_lo  = (f16*)w;   w += (size_t)D3 * DDIM * 2;
  f16* rel_hi  = (f16*)w;   w += (size_t)NRELP * DDIM * 2;
  f16* rel_lo  = (f16*)w;   w += (size_t)NRELP * DDIM * 2;
  f16* relT_hi = (f16*)w;   w += (size_t)DDIM * NRELP * 2;
  f16* relT_lo = (f16*)w;   w += (size_t)DDIM * NRELP * 2;
  float* gieos = (float*)w; w += (size_t)D3 * 4;
  float* gi = (float*)SPhi;               // S/P planes dead when gi/gh live
  float* gh = (float*)SPhi + (size_t)BATCH * D3;

  // prep
  k_split<<<(BATCH * DDIM + 255) / 256, 256, 0, stream>>>(query, x_hi, x_lo, BATCH * DDIM);
  k_split<<<(D3 * DDIM + 255) / 256, 256, 0, stream>>>(W_ih, wih_hi, wih_lo, D3 * DDIM);
  k_split<<<(D3 * DDIM + 255) / 256, 256, 0, stream>>>(W_hh, whh_hi, whh_lo, D3 * DDIM);
  k_prep_rel<<<(NRELP * DDIM + 255) / 256, 256, 0, stream>>>(rel, rel_hi, rel_lo);
  k_transpose_rel<<<dim3(NRELP / 64, DDIM / 64), 256, 0, stream>>>(rel, relT_hi, relT_lo);
  k_gieos<<<D3, 64, 0, stream>>>(W_ih, eos, gieos);

  const int ggrid = BATCH * DDIM / 4 / 256;

  // step A: h1 = GRU(query, 0)   (192 blocks, gy=6: TM=4, TN=6)
  k_gemm8<0, 4, 6><<<192, 512, 0, stream>>>(x_hi, x_lo, DDIM, wih_hi, wih_lo, DDIM,
      gi, nullptr, nullptr, D3, DDIM, 6);
  k_gates<<<ggrid, 256, 0, stream>>>(gi, nullptr, nullptr, b_ih, b_hh, nullptr, hbuf, h_hi, h_lo);

  // step B: h = GRU(eos, h1)
  k_gemm8<0, 4, 6><<<192, 512, 0, stream>>>(h_hi, h_lo, DDIM, whh_hi, whh_lo, DDIM,
      gh, nullptr, nullptr, D3, DDIM, 6);
  k_gates<<<ggrid, 256, 0, stream>>>(nullptr, gieos, gh, b_ih, b_hh, hbuf, hbuf, h_hi, h_lo);

  for (int hop = 0; hop < NHOP; ++hop) {
    // score = h @ relation^T -> S as f16 hi/lo (512 blocks, gy=16: TM=8, TN=8)
    k_gemm8<1, 8, 8><<<512, 512, 0, stream>>>(h_hi, h_lo, DDIM, rel_hi, rel_lo, DDIM,
        nullptr, SPhi, SPlo, NRELP, DDIM, 16);
    // P = softmax(S), hi/lo in place
    k_softmax<<<BATCH, 256, 0, stream>>>(SPhi, SPlo);
    // subgoal partials: P @ relT^T, split-K=4 (256 blocks, gy=2: TM=8, TN=2)
    k_gemm8<0, 8, 2><<<256, 512, 0, stream>>>(SPhi, SPlo, NRELP,
        relT_hi, relT_lo, NRELP, Cpart, nullptr, nullptr, DDIM, 1024, 2);
    // reduce partials -> d_out[:,hop,:] + x hi/lo splits
    k_subred<<<ggrid, 256, 0, stream>>>(Cpart, out, x_hi, x_lo, hop);
    // fused GRU pair: gi = subgoal @ W_ih^T ; gh = h @ W_hh^T
    k_gemm8_gru<<<384, 512, 0, stream>>>(x_hi, x_lo, h_hi, h_lo,
        wih_hi, wih_lo, whh_hi, whh_lo, gi, gh);
    k_gates<<<ggrid, 256, 0, stream>>>(gi, nullptr, gh, b_ih, b_hh, hbuf, hbuf, h_hi, h_lo);
  }

  // masks = 1.0
  k_ones<<<(BATCH * NHOP + 255) / 256, 256, 0, stream>>>(out + (size_t)BATCH * NHOP * DDIM, BATCH * NHOP);
}